// Round 8
// baseline (1559.914 us; speedup 1.0000x reference)
//
#include <hip/hip_runtime.h>

// Problem constants
constexpr int Bsz = 2, Tsz = 512, Csz = 1024, Hsz = 16, Dsz = 64, CSz = 64;
constexpr int NCHUNK = 8, OW = 8;

// Polar Express quintic coefficients (first NS_STEPS=5 rows)
__constant__ float PE_A[5] = {8.28721201814563f, 4.107059111542203f, 3.9486908534822946f,
                              3.3184196573706015f, 2.300652019954817f};
__constant__ float PE_B[5] = {-23.595886519098837f, -2.9478499167379106f, -2.908902115962949f,
                              -2.488488024314874f, -1.6689039845747493f};
__constant__ float PE_C[5] = {17.300387312530933f, 0.5448431082926601f, 0.5518191394370137f,
                              0.51004894012372f, 0.4188073119525673f};

typedef __attribute__((ext_vector_type(8))) _Float16 half8;
typedef __attribute__((ext_vector_type(16))) float f32x16;

constexpr float INV_S = 1.0f / 2048.0f;

struct HL { _Float16 h, l; };

// fp32 v ~= hi + (lo/2048); hi/lo f16 RN; lo pre-scaled into normal range.
__device__ __forceinline__ HL split_f16(float v) {
  HL o;
  o.h = (_Float16)v;                 // RN
  float r = v - (float)o.h;          // exact residual
  o.l = (_Float16)(r * 2048.0f);
  return o;
}

// ---------------------------------------------------------------------------
// fp32 tiled GEMM:  O[m][n] = sum_k A[m][k] * W[n][k]   (A @ W.T)
// ---------------------------------------------------------------------------
__global__ __launch_bounds__(256) void gemm_nt(const float* __restrict__ A,
                                               const float* __restrict__ W,
                                               float* __restrict__ O,
                                               int M, int N, int K) {
  __shared__ float As[16][68];
  __shared__ float Ws[16][68];
  const int tid = threadIdx.x;
  const int m0 = blockIdx.x * 64, n0 = blockIdx.y * 64;
  const int tm = tid & 15, tn = tid >> 4;
  const int lr = tid >> 2, lk = (tid & 3) << 2;
  float acc[4][4] = {};
  for (int k0 = 0; k0 < K; k0 += 16) {
    float4 av = *(const float4*)(A + (size_t)(m0 + lr) * K + k0 + lk);
    float4 wv = *(const float4*)(W + (size_t)(n0 + lr) * K + k0 + lk);
    __syncthreads();
    As[lk + 0][lr] = av.x; As[lk + 1][lr] = av.y; As[lk + 2][lr] = av.z; As[lk + 3][lr] = av.w;
    Ws[lk + 0][lr] = wv.x; Ws[lk + 1][lr] = wv.y; Ws[lk + 2][lr] = wv.z; Ws[lk + 3][lr] = wv.w;
    __syncthreads();
#pragma unroll
    for (int k = 0; k < 16; ++k) {
      float4 a4 = *(const float4*)&As[k][tm << 2];
      float4 w4 = *(const float4*)&Ws[k][tn << 2];
      float a_[4] = {a4.x, a4.y, a4.z, a4.w};
      float w_[4] = {w4.x, w4.y, w4.z, w4.w};
#pragma unroll
      for (int i = 0; i < 4; ++i)
#pragma unroll
        for (int j = 0; j < 4; ++j) acc[i][j] += a_[i] * w_[j];
    }
  }
#pragma unroll
  for (int i = 0; i < 4; ++i) {
    float4 o = {acc[i][0], acc[i][1], acc[i][2], acc[i][3]};
    *(float4*)(O + (size_t)(m0 + (tm << 2) + i) * N + n0 + (tn << 2)) = o;
  }
}

// ---------------------------------------------------------------------------
// Gates
// ---------------------------------------------------------------------------
__global__ __launch_bounds__(64) void gates_kernel(const float* __restrict__ x,
                                                   const float* __restrict__ Wa,
                                                   const float* __restrict__ We,
                                                   const float* __restrict__ Wt,
                                                   const float* __restrict__ Wg,
                                                   float* __restrict__ ga, float* __restrict__ ge,
                                                   float* __restrict__ gt, float* __restrict__ gg) {
  __shared__ float xs[Csz];
  const int bt = blockIdx.x;
  const int tid = threadIdx.x;
  const float* xr = x + (size_t)bt * Csz;
  for (int i = tid * 4; i < Csz; i += 64 * 4) *(float4*)&xs[i] = *(const float4*)&xr[i];
  __syncthreads();
  const int gsel = tid >> 4, h = tid & 15;
  const float* Wrow = (gsel == 0 ? Wa : gsel == 1 ? We : gsel == 2 ? Wt : Wg) + (size_t)h * Csz;
  float acc = 0.f;
  for (int i = 0; i < Csz; i += 4) {
    float4 w4 = *(const float4*)&Wrow[i];
    acc += xs[i] * w4.x + xs[i + 1] * w4.y + xs[i + 2] * w4.z + xs[i + 3] * w4.w;
  }
  float s = 1.f / (1.f + expf(-acc));
  float* outp = (gsel == 0 ? ga : gsel == 1 ? ge : gsel == 2 ? gt : gg);
  outp[(size_t)bt * Hsz + h] = s;
}

// ---------------------------------------------------------------------------
// Causal depthwise conv (K=4) + optional rms_norm/poly
// ---------------------------------------------------------------------------
__global__ __launch_bounds__(256) void conv_kernel(const float* __restrict__ lin,
                                                   const float* __restrict__ w,
                                                   const float* __restrict__ bias,
                                                   float* __restrict__ out, int do_norm) {
  const int bt = blockIdx.x;
  const int b = bt >> 9, t = bt & 511;
  const int tid = threadIdx.x;
  const int c0 = tid << 2;
  float4 bv = *(const float4*)&bias[c0];
  float v0 = bv.x, v1 = bv.y, v2 = bv.z, v3 = bv.w;
  float4 w0 = *(const float4*)&w[(c0 + 0) * 4];
  float4 w1 = *(const float4*)&w[(c0 + 1) * 4];
  float4 w2 = *(const float4*)&w[(c0 + 2) * 4];
  float4 w3 = *(const float4*)&w[(c0 + 3) * 4];
  const float* base = lin + (size_t)b * Tsz * Csz + c0;
#pragma unroll
  for (int j = 0; j < 4; ++j) {
    int tt = t - 3 + j;
    if (tt < 0) continue;
    float4 xv = *(const float4*)(base + (size_t)tt * Csz);
    v0 += xv.x * (&w0.x)[j];
    v1 += xv.y * (&w1.x)[j];
    v2 += xv.z * (&w2.x)[j];
    v3 += xv.w * (&w3.x)[j];
  }
  if (do_norm) {
    float ss = v0 * v0 + v1 * v1 + v2 * v2 + v3 * v3;
    ss += __shfl_xor(ss, 1, 16);
    ss += __shfl_xor(ss, 2, 16);
    ss += __shfl_xor(ss, 4, 16);
    ss += __shfl_xor(ss, 8, 16);
    float scl = rsqrtf(ss * (1.f / 64.f) + 1e-6f);
    v0 *= scl; v1 *= scl; v2 *= scl; v3 *= scl;
    v0 += 0.5f * v0 * v0; v1 += 0.5f * v1 * v1; v2 += 0.5f * v2 * v2; v3 += 0.5f * v3 * v3;
  }
  float4 o = {v0, v1, v2, v3};
  *(float4*)(out + (size_t)bt * Csz + c0) = o;
}

// ---------------------------------------------------------------------------
// rms_norm for y
// ---------------------------------------------------------------------------
__global__ __launch_bounds__(256) void rms_kernel(const float* __restrict__ in,
                                                  float* __restrict__ out) {
  const int bt = blockIdx.x;
  const int tid = threadIdx.x;
  const int c0 = tid << 2;
  float4 xv = *(const float4*)(in + (size_t)bt * Csz + c0);
  float ss = xv.x * xv.x + xv.y * xv.y + xv.z * xv.z + xv.w * xv.w;
  ss += __shfl_xor(ss, 1, 16);
  ss += __shfl_xor(ss, 2, 16);
  ss += __shfl_xor(ss, 4, 16);
  ss += __shfl_xor(ss, 8, 16);
  float scl = rsqrtf(ss * (1.f / 64.f) + 1e-6f);
  float4 o = {xv.x * scl, xv.y * scl, xv.z * scl, xv.w * scl};
  *(float4*)(out + (size_t)bt * Csz + c0) = o;
}

// ---------------------------------------------------------------------------
// B1+B2 fused: err = M k - v, then omega window + momentum scan.
// ---------------------------------------------------------------------------
__global__ __launch_bounds__(256) void mom_scan_kernel(const float* __restrict__ Mst,
                                                       const float* __restrict__ kp,
                                                       const float* __restrict__ vp,
                                                       const float* __restrict__ geta,
                                                       const float* __restrict__ gtheta,
                                                       const float* __restrict__ ggamma,
                                                       float* __restrict__ Sst,
                                                       float* __restrict__ chunkS, int ci) {
  __shared__ float Ml[4 * Dsz];
  __shared__ float errl[256];
  __shared__ float kkl[CSz * Dsz];
  __shared__ float gl[CSz], el[CSz], tl[CSz];
  const int blk = blockIdx.x;
  const int bh = blk >> 4, eb = blk & 15;
  const int b = bh >> 4, h = bh & 15;
  const int tid = threadIdx.x;
  Ml[tid & 255] = Mst[(size_t)bh * 4096 + eb * 4 * 64 + tid];
#pragma unroll
  for (int i = 0; i < 16; ++i) {
    int idx = i * 256 + tid;
    int t = idx >> 6, k = idx & 63;
    kkl[idx] = kp[(((size_t)b * Tsz + ci * CSz + t) * Hsz + h) * Dsz + k];
  }
  if (tid < CSz) {
    size_t gi = ((size_t)b * Tsz + ci * CSz + tid) * Hsz + h;
    gl[tid] = ggamma[gi];
    el[tid] = geta[gi];
    tl[tid] = gtheta[gi];
  }
  __syncthreads();
  {
    const int tt = tid >> 2, vl = tid & 3;
    float acc = 0.f;
#pragma unroll 8
    for (int k = 0; k < Dsz; ++k) acc += Ml[vl * 64 + k] * kkl[tt * 64 + k];
    float vv = vp[(((size_t)b * Tsz + ci * CSz + tt) * Hsz + h) * Dsz + eb * 4 + vl];
    errl[tt * 4 + vl] = acc - vv;
  }
  __syncthreads();
  const int e = eb * 256 + tid;
  const int vloc = tid >> 6;
  const int k = tid & 63;
  float S = Sst[(size_t)bh * 4096 + e];
  float ring[OW];
  float wsum = 0.f;
  float* outp = chunkS + (size_t)bh * CSz * 4096 + e;
#pragma unroll
  for (int t = 0; t < CSz; ++t) {
    float u = 2.f * errl[t * 4 + vloc] * kkl[t * 64 + k];
    float val = gl[t] * u;
    wsum += val;
    if (t >= OW) wsum -= ring[t & (OW - 1)];
    ring[t & (OW - 1)] = val;
    S = tl[t] * S - el[t] * wsum;
    outp[(size_t)t * 4096] = S;
  }
  Sst[(size_t)bh * 4096 + e] = S;
}

// ---------------------------------------------------------------------------
// B3: Polar Express — fully register-resident, one WAVE per 64x64 matrix.
// No LDS, no barriers. Cross-lane movement: half-wave __shfl_xor(32).
// Init is THREE-PASS (norm / rows / cols) to avoid holding 128 fp32 temps
// live against the fragment arrays (the round-7 spill cause).
// ---------------------------------------------------------------------------
__device__ __forceinline__ void mm4(const half8 (&Ph)[2][4], const half8 (&Pl)[2][4],
                                    const half8 (&Qh)[2][4], const half8 (&Ql)[2][4],
                                    f32x16 (&aH)[2][2], f32x16 (&aL)[2][2]) {
#pragma unroll
  for (int ks = 0; ks < 4; ++ks)
#pragma unroll
    for (int tm = 0; tm < 2; ++tm)
#pragma unroll
      for (int tn = 0; tn < 2; ++tn) {
        aH[tm][tn] = __builtin_amdgcn_mfma_f32_32x32x16_f16(Ph[tm][ks], Qh[tn][ks], aH[tm][tn], 0, 0, 0);
        aL[tm][tn] = __builtin_amdgcn_mfma_f32_32x32x16_f16(Ph[tm][ks], Ql[tn][ks], aL[tm][tn], 0, 0, 0);
        aL[tm][tn] = __builtin_amdgcn_mfma_f32_32x32x16_f16(Pl[tm][ks], Qh[tn][ks], aL[tm][tn], 0, 0, 0);
      }
}

// Build frags of transpose-of-C-matrix (== matrix itself when symmetric).
__device__ __forceinline__ void mkfrags(const f32x16 (&Cv)[2][2], int q,
                                        half8 (&Fh)[2][4], half8 (&Fl)[2][4]) {
#pragma unroll
  for (int base = 0; base < 2; ++base)
#pragma unroll
    for (int ks = 0; ks < 4; ++ks) {
      const int tr2 = ks >> 1, s = ks & 1;
      float j03[4], j47[4];
#pragma unroll
      for (int d = 0; d < 4; ++d) {
        float a = Cv[tr2][base][8 * s + d];
        float b = Cv[tr2][base][8 * s + 4 + d];
        float sendv = q ? a : b;
        float recv = __shfl_xor(sendv, 32, 64);
        j03[d] = q ? recv : a;
        j47[d] = q ? b : recv;
      }
      half8 fh, fl;
#pragma unroll
      for (int d = 0; d < 4; ++d) {
        HL s0 = split_f16(j03[d]); fh[d] = s0.h; fl[d] = s0.l;
        HL s1 = split_f16(j47[d]); fh[4 + d] = s1.h; fl[4 + d] = s1.l;
      }
      Fh[base][ks] = fh; Fl[base][ks] = fl;
    }
}

__global__ __launch_bounds__(256, 1) void pe_reg_kernel(float* __restrict__ chunkS) {
  const int tid = threadIdx.x;
  const int lane = tid & 63;
  const int wv = tid >> 6;
  const int q = lane >> 5;
  const int ccol = lane & 31;
  float* G = chunkS + ((size_t)blockIdx.x * 4 + wv) * 4096;

  // ---- pass 1: Frobenius norm only (values discarded -> low pressure) ----
  float ss = 0.f;
#pragma unroll
  for (int base = 0; base < 2; ++base)
#pragma unroll
    for (int ks = 0; ks < 4; ++ks) {
      int row = 32 * base + ccol;
      int c0 = 16 * ks + 8 * q;
      float4 v0 = *(const float4*)(G + row * 64 + c0);
      float4 v1 = *(const float4*)(G + row * 64 + c0 + 4);
      ss += v0.x * v0.x + v0.y * v0.y + v0.z * v0.z + v0.w * v0.w;
      ss += v1.x * v1.x + v1.y * v1.y + v1.z * v1.z + v1.w * v1.w;
    }
#pragma unroll
  for (int off = 32; off; off >>= 1) ss += __shfl_xor(ss, off, 64);
  float scale = 1.f / ((sqrtf(ss) + 1e-7f) * 1.01f);

  half8 Xfh[2][4], Xfl[2][4], Xch[2][4], Xcl[2][4];
  // ---- pass 2: row-frags (coalesced re-read, split immediately) ----
#pragma unroll
  for (int base = 0; base < 2; ++base)
#pragma unroll
    for (int ks = 0; ks < 4; ++ks) {
      int row = 32 * base + ccol;
      int c0 = 16 * ks + 8 * q;
      float4 v0 = *(const float4*)(G + row * 64 + c0);
      float4 v1 = *(const float4*)(G + row * 64 + c0 + 4);
      half8 fh, fl;
      HL s0;
      s0 = split_f16(v0.x * scale); fh[0] = s0.h; fl[0] = s0.l;
      s0 = split_f16(v0.y * scale); fh[1] = s0.h; fl[1] = s0.l;
      s0 = split_f16(v0.z * scale); fh[2] = s0.h; fl[2] = s0.l;
      s0 = split_f16(v0.w * scale); fh[3] = s0.h; fl[3] = s0.l;
      s0 = split_f16(v1.x * scale); fh[4] = s0.h; fl[4] = s0.l;
      s0 = split_f16(v1.y * scale); fh[5] = s0.h; fl[5] = s0.l;
      s0 = split_f16(v1.z * scale); fh[6] = s0.h; fl[6] = s0.l;
      s0 = split_f16(v1.w * scale); fh[7] = s0.h; fl[7] = s0.l;
      Xfh[base][ks] = fh; Xfl[base][ks] = fl;
    }
  // ---- pass 3: col-frags (strided scalar reads, split immediately) ----
#pragma unroll
  for (int base = 0; base < 2; ++base)
#pragma unroll
    for (int ks = 0; ks < 4; ++ks) {
      half8 ch, cl;
#pragma unroll
      for (int j = 0; j < 8; ++j) {
        float v = G[(16 * ks + 8 * q + j) * 64 + 32 * base + ccol];
        HL s2 = split_f16(v * scale);
        ch[j] = s2.h; cl[j] = s2.l;
      }
      Xch[base][ks] = ch; Xcl[base][ks] = cl;
    }

  f32x16 aH[2][2], aL[2][2];
  half8 Fh[2][4], Fl[2][4];

  for (int it = 0; it < 5; ++it) {
    const float ca = PE_A[it], cb = PE_B[it], cc = PE_C[it];
    // ---- A = X·X^T ----
#pragma unroll
    for (int tm = 0; tm < 2; ++tm)
#pragma unroll
      for (int tn = 0; tn < 2; ++tn)
#pragma unroll
        for (int r = 0; r < 16; ++r) { aH[tm][tn][r] = 0.f; aL[tm][tn][r] = 0.f; }
    mm4(Xfh, Xfl, Xfh, Xfl, aH, aL);
#pragma unroll
    for (int tm = 0; tm < 2; ++tm)
#pragma unroll
      for (int tn = 0; tn < 2; ++tn)
#pragma unroll
        for (int r = 0; r < 16; ++r) aH[tm][tn][r] += aL[tm][tn][r] * INV_S;  // A values
    mkfrags(aH, q, Fh, Fl);                                                   // A-frags
    // ---- A2 = A·A with acc preloaded (b/c)·A ----
    const float bc = cb / cc;
#pragma unroll
    for (int tm = 0; tm < 2; ++tm)
#pragma unroll
      for (int tn = 0; tn < 2; ++tn)
#pragma unroll
        for (int r = 0; r < 16; ++r) { aH[tm][tn][r] *= bc; aL[tm][tn][r] = 0.f; }
    mm4(Fh, Fl, Fh, Fl, aH, aL);
    // ---- Bm = c·(A2 + (b/c)A) + a·I  (C-layout) ----
#pragma unroll
    for (int tm = 0; tm < 2; ++tm)
#pragma unroll
      for (int tn = 0; tn < 2; ++tn)
#pragma unroll
        for (int r = 0; r < 16; ++r) {
          float bm = cc * (aH[tm][tn][r] + aL[tm][tn][r] * INV_S);
          int rloc = 4 * q + (r & 3) + ((r >> 2) << 3);
          if (tm == tn && rloc == ccol) bm += ca;
          aH[tm][tn][r] = bm;
        }
    mkfrags(aH, q, Fh, Fl);                                                   // Bm-frags
    if (it < 4) {
      // ---- X'^T = X^T·Bm  ->  new row-frags of X' ----
#pragma unroll
      for (int tm = 0; tm < 2; ++tm)
#pragma unroll
        for (int tn = 0; tn < 2; ++tn)
#pragma unroll
          for (int r = 0; r < 16; ++r) { aH[tm][tn][r] = 0.f; aL[tm][tn][r] = 0.f; }
      mm4(Xch, Xcl, Fh, Fl, aH, aL);
#pragma unroll
      for (int tm = 0; tm < 2; ++tm)
#pragma unroll
        for (int tn = 0; tn < 2; ++tn)
#pragma unroll
          for (int r = 0; r < 16; ++r) aH[tm][tn][r] += aL[tm][tn][r] * INV_S;
      mkfrags(aH, q, Xfh, Xfl);
      // ---- X' = Bm·X  ->  new col-frags of X' ----
#pragma unroll
      for (int tm = 0; tm < 2; ++tm)
#pragma unroll
        for (int tn = 0; tn < 2; ++tn)
#pragma unroll
          for (int r = 0; r < 16; ++r) { aH[tm][tn][r] = 0.f; aL[tm][tn][r] = 0.f; }
      mm4(Fh, Fl, Xch, Xcl, aH, aL);
#pragma unroll
      for (int tm = 0; tm < 2; ++tm)
#pragma unroll
        for (int tn = 0; tn < 2; ++tn)
#pragma unroll
          for (int r = 0; r < 16; ++r) aH[tm][tn][r] += aL[tm][tn][r] * INV_S;
      mkfrags(aH, q, Xch, Xcl);
    } else {
      // ---- final: X' = Bm·X, store fp32 row-major ----
#pragma unroll
      for (int tm = 0; tm < 2; ++tm)
#pragma unroll
        for (int tn = 0; tn < 2; ++tn)
#pragma unroll
          for (int r = 0; r < 16; ++r) { aH[tm][tn][r] = 0.f; aL[tm][tn][r] = 0.f; }
      mm4(Fh, Fl, Xch, Xcl, aH, aL);
#pragma unroll
      for (int tm = 0; tm < 2; ++tm)
#pragma unroll
        for (int tn = 0; tn < 2; ++tn)
#pragma unroll
          for (int r = 0; r < 16; ++r) {
            float xv = aH[tm][tn][r] + aL[tm][tn][r] * INV_S;
            int row = 32 * tm + 4 * q + (r & 3) + ((r >> 2) << 3);
            int col = 32 * tn + ccol;
            G[row * 64 + col] = xv;
          }
    }
  }
}

// ---------------------------------------------------------------------------
// B4: memory scan + read
// ---------------------------------------------------------------------------
__global__ __launch_bounds__(256) void mem_scan_kernel(const float* __restrict__ chunkS,
                                                       const float* __restrict__ qp,
                                                       const float* __restrict__ galpha,
                                                       float* __restrict__ Mst,
                                                       float* __restrict__ ybuf, int ci) {
  __shared__ float ql[CSz * Dsz];
  __shared__ float al[CSz];
  const int blk = blockIdx.x;
  const int bh = blk >> 4, eb = blk & 15;
  const int b = bh >> 4, h = bh & 15;
  const int tid = threadIdx.x;
  const int w = tid >> 6, lane = tid & 63;
  const int v = eb * 4 + w, k = lane;
  for (int i = tid; i < CSz * Dsz; i += 256) {
    int t = i >> 6, kk = i & 63;
    ql[i] = qp[(((size_t)b * Tsz + ci * CSz + t) * Hsz + h) * Dsz + kk];
  }
  if (tid < CSz) al[tid] = galpha[((size_t)b * Tsz + ci * CSz + tid) * Hsz + h];
  __syncthreads();
  float m = Mst[(size_t)bh * 4096 + v * 64 + k];
  const float* Xo = chunkS + (size_t)bh * CSz * 4096;
  for (int t = 0; t < CSz; ++t) {
    m = al[t] * m + Xo[(size_t)t * 4096 + v * 64 + k];
    float p = m * ql[t * 64 + k];
#pragma unroll
    for (int off = 32; off; off >>= 1) p += __shfl_xor(p, off, 64);
    if (lane == 0) ybuf[(((size_t)b * Tsz + ci * CSz + t) * Hsz + h) * Dsz + v] = p;
  }
  Mst[(size_t)bh * 4096 + v * 64 + k] = m;
}

// ---------------------------------------------------------------------------
extern "C" void kernel_launch(void* const* d_in, const int* in_sizes, int n_in,
                              void* d_out, int out_size, void* d_ws, size_t ws_size,
                              hipStream_t stream) {
  (void)in_sizes; (void)n_in; (void)out_size; (void)ws_size;
  const float* x   = (const float*)d_in[0];
  const float* Wq  = (const float*)d_in[1];
  const float* Wk  = (const float*)d_in[2];
  const float* Wv  = (const float*)d_in[3];
  const float* Wo  = (const float*)d_in[4];
  const float* cqw = (const float*)d_in[5];
  const float* cqb = (const float*)d_in[6];
  const float* ckw = (const float*)d_in[7];
  const float* ckb = (const float*)d_in[8];
  const float* cvw = (const float*)d_in[9];
  const float* cvb = (const float*)d_in[10];
  const float* Wa  = (const float*)d_in[11];
  const float* We  = (const float*)d_in[12];
  const float* Wt  = (const float*)d_in[13];
  const float* Wg  = (const float*)d_in[14];
  float* out = (float*)d_out;

  float* p = (float*)d_ws;
  const size_t NBTC = (size_t)Bsz * Tsz * Csz;
  const size_t NBTH = (size_t)Bsz * Tsz * Hsz;
  const size_t NMAT = (size_t)Bsz * Hsz * Dsz * Dsz;
  float* qlin = p; p += NBTC;
  float* klin = p; p += NBTC;
  float* vlin = p; p += NBTC;
  float* qp   = p; p += NBTC;
  float* kp   = p; p += NBTC;
  float* vp   = p; p += NBTC;
  float* ga   = p; p += NBTH;
  float* ge   = p; p += NBTH;
  float* gt   = p; p += NBTH;
  float* gg   = p; p += NBTH;
  float* Mst  = p; p += NMAT;
  float* Sst  = p; p += NMAT;
  float* chS  = p; p += (size_t)Bsz * Hsz * CSz * Dsz * Dsz;
  float* ybuf = p; p += NBTC;
  float* ynrm = p; p += NBTC;

  hipMemsetAsync(Mst, 0, NMAT * sizeof(float), stream);
  hipMemsetAsync(Sst, 0, NMAT * sizeof(float), stream);

  dim3 gg16(16, 16);
  gemm_nt<<<gg16, 256, 0, stream>>>(x, Wq, qlin, Bsz * Tsz, Csz, Csz);
  gemm_nt<<<gg16, 256, 0, stream>>>(x, Wk, klin, Bsz * Tsz, Csz, Csz);
  gemm_nt<<<gg16, 256, 0, stream>>>(x, Wv, vlin, Bsz * Tsz, Csz, Csz);
  gates_kernel<<<Bsz * Tsz, 64, 0, stream>>>(x, Wa, We, Wt, Wg, ga, ge, gt, gg);
  conv_kernel<<<Bsz * Tsz, 256, 0, stream>>>(qlin, cqw, cqb, qp, 1);
  conv_kernel<<<Bsz * Tsz, 256, 0, stream>>>(klin, ckw, ckb, kp, 1);
  conv_kernel<<<Bsz * Tsz, 256, 0, stream>>>(vlin, cvw, cvb, vp, 0);

  for (int ci = 0; ci < NCHUNK; ++ci) {
    mom_scan_kernel<<<Bsz * Hsz * 16, 256, 0, stream>>>(Mst, kp, vp, ge, gt, gg, Sst, chS, ci);
    pe_reg_kernel<<<Bsz * Hsz * CSz / 4, 256, 0, stream>>>(chS);
    mem_scan_kernel<<<Bsz * Hsz * 16, 256, 0, stream>>>(chS, qp, ga, Mst, ybuf, ci);
  }

  rms_kernel<<<Bsz * Tsz, 256, 0, stream>>>(ybuf, ynrm);
  gemm_nt<<<gg16, 256, 0, stream>>>(ynrm, Wo, out, Bsz * Tsz, Csz, Csz);
}

// Round 9
// 1485.065 us; speedup vs baseline: 1.0504x; 1.0504x over previous
//
#include <hip/hip_runtime.h>

// Problem constants
constexpr int Bsz = 2, Tsz = 512, Csz = 1024, Hsz = 16, Dsz = 64, CSz = 64;
constexpr int NCHUNK = 8, OW = 8;

// Polar Express quintic coefficients (first NS_STEPS=5 rows)
__constant__ float PE_A[5] = {8.28721201814563f, 4.107059111542203f, 3.9486908534822946f,
                              3.3184196573706015f, 2.300652019954817f};
__constant__ float PE_B[5] = {-23.595886519098837f, -2.9478499167379106f, -2.908902115962949f,
                              -2.488488024314874f, -1.6689039845747493f};
__constant__ float PE_C[5] = {17.300387312530933f, 0.5448431082926601f, 0.5518191394370137f,
                              0.51004894012372f, 0.4188073119525673f};

typedef __attribute__((ext_vector_type(8))) _Float16 half8;
typedef __attribute__((ext_vector_type(16))) float f32x16;

constexpr float INV_S = 1.0f / 2048.0f;

struct HL { _Float16 h, l; };

// fp32 v ~= hi + (lo/2048); hi/lo f16 RN; lo pre-scaled into normal range.
__device__ __forceinline__ HL split_f16(float v) {
  HL o;
  o.h = (_Float16)v;                 // RN
  float r = v - (float)o.h;          // exact residual
  o.l = (_Float16)(r * 2048.0f);
  return o;
}

// ---------------------------------------------------------------------------
// fp32 tiled GEMM:  O[m][n] = sum_k A[m][k] * W[n][k]   (A @ W.T)
// ---------------------------------------------------------------------------
__global__ __launch_bounds__(256) void gemm_nt(const float* __restrict__ A,
                                               const float* __restrict__ W,
                                               float* __restrict__ O,
                                               int M, int N, int K) {
  __shared__ float As[16][68];
  __shared__ float Ws[16][68];
  const int tid = threadIdx.x;
  const int m0 = blockIdx.x * 64, n0 = blockIdx.y * 64;
  const int tm = tid & 15, tn = tid >> 4;
  const int lr = tid >> 2, lk = (tid & 3) << 2;
  float acc[4][4] = {};
  for (int k0 = 0; k0 < K; k0 += 16) {
    float4 av = *(const float4*)(A + (size_t)(m0 + lr) * K + k0 + lk);
    float4 wv = *(const float4*)(W + (size_t)(n0 + lr) * K + k0 + lk);
    __syncthreads();
    As[lk + 0][lr] = av.x; As[lk + 1][lr] = av.y; As[lk + 2][lr] = av.z; As[lk + 3][lr] = av.w;
    Ws[lk + 0][lr] = wv.x; Ws[lk + 1][lr] = wv.y; Ws[lk + 2][lr] = wv.z; Ws[lk + 3][lr] = wv.w;
    __syncthreads();
#pragma unroll
    for (int k = 0; k < 16; ++k) {
      float4 a4 = *(const float4*)&As[k][tm << 2];
      float4 w4 = *(const float4*)&Ws[k][tn << 2];
      float a_[4] = {a4.x, a4.y, a4.z, a4.w};
      float w_[4] = {w4.x, w4.y, w4.z, w4.w};
#pragma unroll
      for (int i = 0; i < 4; ++i)
#pragma unroll
        for (int j = 0; j < 4; ++j) acc[i][j] += a_[i] * w_[j];
    }
  }
#pragma unroll
  for (int i = 0; i < 4; ++i) {
    float4 o = {acc[i][0], acc[i][1], acc[i][2], acc[i][3]};
    *(float4*)(O + (size_t)(m0 + (tm << 2) + i) * N + n0 + (tn << 2)) = o;
  }
}

// ---------------------------------------------------------------------------
// Gates
// ---------------------------------------------------------------------------
__global__ __launch_bounds__(64) void gates_kernel(const float* __restrict__ x,
                                                   const float* __restrict__ Wa,
                                                   const float* __restrict__ We,
                                                   const float* __restrict__ Wt,
                                                   const float* __restrict__ Wg,
                                                   float* __restrict__ ga, float* __restrict__ ge,
                                                   float* __restrict__ gt, float* __restrict__ gg) {
  __shared__ float xs[Csz];
  const int bt = blockIdx.x;
  const int tid = threadIdx.x;
  const float* xr = x + (size_t)bt * Csz;
  for (int i = tid * 4; i < Csz; i += 64 * 4) *(float4*)&xs[i] = *(const float4*)&xr[i];
  __syncthreads();
  const int gsel = tid >> 4, h = tid & 15;
  const float* Wrow = (gsel == 0 ? Wa : gsel == 1 ? We : gsel == 2 ? Wt : Wg) + (size_t)h * Csz;
  float acc = 0.f;
  for (int i = 0; i < Csz; i += 4) {
    float4 w4 = *(const float4*)&Wrow[i];
    acc += xs[i] * w4.x + xs[i + 1] * w4.y + xs[i + 2] * w4.z + xs[i + 3] * w4.w;
  }
  float s = 1.f / (1.f + expf(-acc));
  float* outp = (gsel == 0 ? ga : gsel == 1 ? ge : gsel == 2 ? gt : gg);
  outp[(size_t)bt * Hsz + h] = s;
}

// ---------------------------------------------------------------------------
// Causal depthwise conv (K=4) + optional rms_norm/poly
// ---------------------------------------------------------------------------
__global__ __launch_bounds__(256) void conv_kernel(const float* __restrict__ lin,
                                                   const float* __restrict__ w,
                                                   const float* __restrict__ bias,
                                                   float* __restrict__ out, int do_norm) {
  const int bt = blockIdx.x;
  const int b = bt >> 9, t = bt & 511;
  const int tid = threadIdx.x;
  const int c0 = tid << 2;
  float4 bv = *(const float4*)&bias[c0];
  float v0 = bv.x, v1 = bv.y, v2 = bv.z, v3 = bv.w;
  float4 w0 = *(const float4*)&w[(c0 + 0) * 4];
  float4 w1 = *(const float4*)&w[(c0 + 1) * 4];
  float4 w2 = *(const float4*)&w[(c0 + 2) * 4];
  float4 w3 = *(const float4*)&w[(c0 + 3) * 4];
  const float* base = lin + (size_t)b * Tsz * Csz + c0;
#pragma unroll
  for (int j = 0; j < 4; ++j) {
    int tt = t - 3 + j;
    if (tt < 0) continue;
    float4 xv = *(const float4*)(base + (size_t)tt * Csz);
    v0 += xv.x * (&w0.x)[j];
    v1 += xv.y * (&w1.x)[j];
    v2 += xv.z * (&w2.x)[j];
    v3 += xv.w * (&w3.x)[j];
  }
  if (do_norm) {
    float ss = v0 * v0 + v1 * v1 + v2 * v2 + v3 * v3;
    ss += __shfl_xor(ss, 1, 16);
    ss += __shfl_xor(ss, 2, 16);
    ss += __shfl_xor(ss, 4, 16);
    ss += __shfl_xor(ss, 8, 16);
    float scl = rsqrtf(ss * (1.f / 64.f) + 1e-6f);
    v0 *= scl; v1 *= scl; v2 *= scl; v3 *= scl;
    v0 += 0.5f * v0 * v0; v1 += 0.5f * v1 * v1; v2 += 0.5f * v2 * v2; v3 += 0.5f * v3 * v3;
  }
  float4 o = {v0, v1, v2, v3};
  *(float4*)(out + (size_t)bt * Csz + c0) = o;
}

// ---------------------------------------------------------------------------
// rms_norm for y
// ---------------------------------------------------------------------------
__global__ __launch_bounds__(256) void rms_kernel(const float* __restrict__ in,
                                                  float* __restrict__ out) {
  const int bt = blockIdx.x;
  const int tid = threadIdx.x;
  const int c0 = tid << 2;
  float4 xv = *(const float4*)(in + (size_t)bt * Csz + c0);
  float ss = xv.x * xv.x + xv.y * xv.y + xv.z * xv.z + xv.w * xv.w;
  ss += __shfl_xor(ss, 1, 16);
  ss += __shfl_xor(ss, 2, 16);
  ss += __shfl_xor(ss, 4, 16);
  ss += __shfl_xor(ss, 8, 16);
  float scl = rsqrtf(ss * (1.f / 64.f) + 1e-6f);
  float4 o = {xv.x * scl, xv.y * scl, xv.z * scl, xv.w * scl};
  *(float4*)(out + (size_t)bt * Csz + c0) = o;
}

// ---------------------------------------------------------------------------
// B1+B2 fused: err = M k - v, then omega window + momentum scan.
// ---------------------------------------------------------------------------
__global__ __launch_bounds__(256) void mom_scan_kernel(const float* __restrict__ Mst,
                                                       const float* __restrict__ kp,
                                                       const float* __restrict__ vp,
                                                       const float* __restrict__ geta,
                                                       const float* __restrict__ gtheta,
                                                       const float* __restrict__ ggamma,
                                                       float* __restrict__ Sst,
                                                       float* __restrict__ chunkS, int ci) {
  __shared__ float Ml[4 * Dsz];
  __shared__ float errl[256];
  __shared__ float kkl[CSz * Dsz];
  __shared__ float gl[CSz], el[CSz], tl[CSz];
  const int blk = blockIdx.x;
  const int bh = blk >> 4, eb = blk & 15;
  const int b = bh >> 4, h = bh & 15;
  const int tid = threadIdx.x;
  Ml[tid & 255] = Mst[(size_t)bh * 4096 + eb * 4 * 64 + tid];
#pragma unroll
  for (int i = 0; i < 16; ++i) {
    int idx = i * 256 + tid;
    int t = idx >> 6, k = idx & 63;
    kkl[idx] = kp[(((size_t)b * Tsz + ci * CSz + t) * Hsz + h) * Dsz + k];
  }
  if (tid < CSz) {
    size_t gi = ((size_t)b * Tsz + ci * CSz + tid) * Hsz + h;
    gl[tid] = ggamma[gi];
    el[tid] = geta[gi];
    tl[tid] = gtheta[gi];
  }
  __syncthreads();
  {
    const int tt = tid >> 2, vl = tid & 3;
    float acc = 0.f;
#pragma unroll 8
    for (int k = 0; k < Dsz; ++k) acc += Ml[vl * 64 + k] * kkl[tt * 64 + k];
    float vv = vp[(((size_t)b * Tsz + ci * CSz + tt) * Hsz + h) * Dsz + eb * 4 + vl];
    errl[tt * 4 + vl] = acc - vv;
  }
  __syncthreads();
  const int e = eb * 256 + tid;
  const int vloc = tid >> 6;
  const int k = tid & 63;
  float S = Sst[(size_t)bh * 4096 + e];
  float ring[OW];
  float wsum = 0.f;
  float* outp = chunkS + (size_t)bh * CSz * 4096 + e;
#pragma unroll
  for (int t = 0; t < CSz; ++t) {
    float u = 2.f * errl[t * 4 + vloc] * kkl[t * 64 + k];
    float val = gl[t] * u;
    wsum += val;
    if (t >= OW) wsum -= ring[t & (OW - 1)];
    ring[t & (OW - 1)] = val;
    S = tl[t] * S - el[t] * wsum;
    outp[(size_t)t * 4096] = S;
  }
  Sst[(size_t)bh * 4096 + e] = S;
}

// ---------------------------------------------------------------------------
// B3: Polar Express — register-resident, one WAVE per 64x64 matrix.
// Round-9 restructure: PER-TILE sequential matmuls (one 32-VGPR acc pair
// live), incremental fragment production (mkfrag piece [base][ks] depends
// only on C-tile [ks>>1][base]), and buffer recycling:
//   B1: X row-frags  -> Bm-frags     (Xf dead after stage 1)
//   B2: X col-frags  -> new col-frags (in-place per-tn group, stage 4)
//   B3: A-frags      -> new row-frags (A dead after stage 2)
// The b*A term folds into the left operand: Bm = (cA+bI)·A + aI, with
// A' = cA+bI reconstructed on the fly from A-frags (no fp32 A stored).
// ---------------------------------------------------------------------------
__device__ __forceinline__ void mmtile3(const half8& ph, const half8& pl,
                                        const half8& qh, const half8& ql,
                                        f32x16& aH, f32x16& aL) {
  aH = __builtin_amdgcn_mfma_f32_32x32x16_f16(ph, qh, aH, 0, 0, 0);
  aL = __builtin_amdgcn_mfma_f32_32x32x16_f16(ph, ql, aL, 0, 0, 0);
  aL = __builtin_amdgcn_mfma_f32_32x32x16_f16(pl, qh, aL, 0, 0, 0);
}

// From C-tile values (combined fp32), produce frag piece s (=ks&1) of the
// transpose-of-C (== C itself when symmetric).
__device__ __forceinline__ void mkfrag_piece(const f32x16& Cv, int q, int s,
                                             half8& Fh, half8& Fl) {
#pragma unroll
  for (int d = 0; d < 4; ++d) {
    float a = Cv[8 * s + d];
    float b = Cv[8 * s + 4 + d];
    float sendv = q ? a : b;
    float recv = __shfl_xor(sendv, 32, 64);
    float j03 = q ? recv : a;
    float j47 = q ? b : recv;
    HL s0 = split_f16(j03); Fh[d] = s0.h; Fl[d] = s0.l;
    HL s1 = split_f16(j47); Fh[4 + d] = s1.h; Fl[4 + d] = s1.l;
  }
}

__global__ __launch_bounds__(256, 1) void pe_reg_kernel(float* __restrict__ chunkS) {
  const int tid = threadIdx.x;
  const int lane = tid & 63;
  const int wv = tid >> 6;
  const int q = lane >> 5;
  const int ccol = lane & 31;
  float* G = chunkS + ((size_t)blockIdx.x * 4 + wv) * 4096;

  // ---- pass 1: Frobenius norm only ----
  float ss = 0.f;
#pragma unroll
  for (int base = 0; base < 2; ++base)
#pragma unroll
    for (int ks = 0; ks < 4; ++ks) {
      int row = 32 * base + ccol;
      int c0 = 16 * ks + 8 * q;
      float4 v0 = *(const float4*)(G + row * 64 + c0);
      float4 v1 = *(const float4*)(G + row * 64 + c0 + 4);
      ss += v0.x * v0.x + v0.y * v0.y + v0.z * v0.z + v0.w * v0.w;
      ss += v1.x * v1.x + v1.y * v1.y + v1.z * v1.z + v1.w * v1.w;
    }
#pragma unroll
  for (int off = 32; off; off >>= 1) ss += __shfl_xor(ss, off, 64);
  float scale = 1.f / ((sqrtf(ss) + 1e-7f) * 1.01f);

  // Buffers: B1 = Xf / Bm, B2 = Xc, B3 = A / new Xf
  half8 B1h[2][4], B1l[2][4], B2h[2][4], B2l[2][4], B3h[2][4], B3l[2][4];

  // ---- pass 2: row-frags into B1 ----
#pragma unroll
  for (int base = 0; base < 2; ++base)
#pragma unroll
    for (int ks = 0; ks < 4; ++ks) {
      int row = 32 * base + ccol;
      int c0 = 16 * ks + 8 * q;
      float4 v0 = *(const float4*)(G + row * 64 + c0);
      float4 v1 = *(const float4*)(G + row * 64 + c0 + 4);
      half8 fh, fl;
      HL s0;
      s0 = split_f16(v0.x * scale); fh[0] = s0.h; fl[0] = s0.l;
      s0 = split_f16(v0.y * scale); fh[1] = s0.h; fl[1] = s0.l;
      s0 = split_f16(v0.z * scale); fh[2] = s0.h; fl[2] = s0.l;
      s0 = split_f16(v0.w * scale); fh[3] = s0.h; fl[3] = s0.l;
      s0 = split_f16(v1.x * scale); fh[4] = s0.h; fl[4] = s0.l;
      s0 = split_f16(v1.y * scale); fh[5] = s0.h; fl[5] = s0.l;
      s0 = split_f16(v1.z * scale); fh[6] = s0.h; fl[6] = s0.l;
      s0 = split_f16(v1.w * scale); fh[7] = s0.h; fl[7] = s0.l;
      B1h[base][ks] = fh; B1l[base][ks] = fl;
    }
  // ---- pass 3: col-frags into B2 ----
#pragma unroll
  for (int base = 0; base < 2; ++base)
#pragma unroll
    for (int ks = 0; ks < 4; ++ks) {
      half8 ch, cl;
#pragma unroll
      for (int j = 0; j < 8; ++j) {
        float v = G[(16 * ks + 8 * q + j) * 64 + 32 * base + ccol];
        HL s2 = split_f16(v * scale);
        ch[j] = s2.h; cl[j] = s2.l;
      }
      B2h[base][ks] = ch; B2l[base][ks] = cl;
    }

  for (int it = 0; it < 5; ++it) {
    const float ca = PE_A[it], cb = PE_B[it], cc = PE_C[it];
    // ---- stage 1: A = X·X^T  (B1 row-frags both sides) -> A-frags in B3 ----
#pragma unroll
    for (int tm = 0; tm < 2; ++tm)
#pragma unroll
      for (int tn = 0; tn < 2; ++tn) {
        f32x16 aH, aL;
#pragma unroll
        for (int r = 0; r < 16; ++r) { aH[r] = 0.f; aL[r] = 0.f; }
#pragma unroll
        for (int ks = 0; ks < 4; ++ks)
          mmtile3(B1h[tm][ks], B1l[tm][ks], B1h[tn][ks], B1l[tn][ks], aH, aL);
#pragma unroll
        for (int r = 0; r < 16; ++r) aH[r] += aL[r] * INV_S;
        mkfrag_piece(aH, q, 0, B3h[tn][2 * tm], B3l[tn][2 * tm]);
        mkfrag_piece(aH, q, 1, B3h[tn][2 * tm + 1], B3l[tn][2 * tm + 1]);
      }
    // ---- stage 2: Bm = (cA+bI)·A + aI  -> Bm-frags in B1 (Xf dead) ----
#pragma unroll
    for (int tm = 0; tm < 2; ++tm)
#pragma unroll
      for (int tn = 0; tn < 2; ++tn) {
        f32x16 aH, aL;
#pragma unroll
        for (int r = 0; r < 16; ++r) { aH[r] = 0.f; aL[r] = 0.f; }
#pragma unroll
        for (int ks = 0; ks < 4; ++ks) {
          // A' piece = c*A + b*I, rebuilt from A-frags on the fly
          half8 aph, apl;
#pragma unroll
          for (int j = 0; j < 8; ++j) {
            float v = (float)B3h[tm][ks][j] + (float)B3l[tm][ks][j] * INV_S;
            float ap = cc * v +
                       ((32 * tm + ccol) == (16 * ks + 8 * q + j) ? cb : 0.f);
            HL s0 = split_f16(ap);
            aph[j] = s0.h; apl[j] = s0.l;
          }
          mmtile3(aph, apl, B3h[tn][ks], B3l[tn][ks], aH, aL);
        }
#pragma unroll
        for (int r = 0; r < 16; ++r) {
          float bm = aH[r] + aL[r] * INV_S;
          int rloc = 4 * q + (r & 3) + ((r >> 2) << 3);
          if (tm == tn && rloc == ccol) bm += ca;
          aH[r] = bm;
        }
        mkfrag_piece(aH, q, 0, B1h[tn][2 * tm], B1l[tn][2 * tm]);
        mkfrag_piece(aH, q, 1, B1h[tn][2 * tm + 1], B1l[tn][2 * tm + 1]);
      }
    if (it < 4) {
      // ---- stage 3: X'^T = X^T·Bm  (A-op B2=Xc, B-op B1=Bm) -> new Xf in B3 ----
#pragma unroll
      for (int tm = 0; tm < 2; ++tm)
#pragma unroll
        for (int tn = 0; tn < 2; ++tn) {
          f32x16 aH, aL;
#pragma unroll
          for (int r = 0; r < 16; ++r) { aH[r] = 0.f; aL[r] = 0.f; }
#pragma unroll
          for (int ks = 0; ks < 4; ++ks)
            mmtile3(B2h[tm][ks], B2l[tm][ks], B1h[tn][ks], B1l[tn][ks], aH, aL);
#pragma unroll
          for (int r = 0; r < 16; ++r) aH[r] += aL[r] * INV_S;
          mkfrag_piece(aH, q, 0, B3h[tn][2 * tm], B3l[tn][2 * tm]);
          mkfrag_piece(aH, q, 1, B3h[tn][2 * tm + 1], B3l[tn][2 * tm + 1]);
        }
      // ---- stage 4: X' = Bm·X  (A-op B1=Bm, B-op B2=Xc) -> new Xc in B2 ----
      // Grouped by tn: both tm-tiles computed before overwriting B2[tn].
#pragma unroll
      for (int tn = 0; tn < 2; ++tn) {
        f32x16 Cv0, Cv1;
        {
          f32x16 aH, aL;
#pragma unroll
          for (int r = 0; r < 16; ++r) { aH[r] = 0.f; aL[r] = 0.f; }
#pragma unroll
          for (int ks = 0; ks < 4; ++ks)
            mmtile3(B1h[0][ks], B1l[0][ks], B2h[tn][ks], B2l[tn][ks], aH, aL);
#pragma unroll
          for (int r = 0; r < 16; ++r) Cv0[r] = aH[r] + aL[r] * INV_S;
        }
        {
          f32x16 aH, aL;
#pragma unroll
          for (int r = 0; r < 16; ++r) { aH[r] = 0.f; aL[r] = 0.f; }
#pragma unroll
          for (int ks = 0; ks < 4; ++ks)
            mmtile3(B1h[1][ks], B1l[1][ks], B2h[tn][ks], B2l[tn][ks], aH, aL);
#pragma unroll
          for (int r = 0; r < 16; ++r) Cv1[r] = aH[r] + aL[r] * INV_S;
        }
        mkfrag_piece(Cv0, q, 0, B2h[tn][0], B2l[tn][0]);
        mkfrag_piece(Cv0, q, 1, B2h[tn][1], B2l[tn][1]);
        mkfrag_piece(Cv1, q, 0, B2h[tn][2], B2l[tn][2]);
        mkfrag_piece(Cv1, q, 1, B2h[tn][3], B2l[tn][3]);
      }
      // swap roles: B3 holds new row-frags -> copy into B1 for next iter's stage 1
#pragma unroll
      for (int base = 0; base < 2; ++base)
#pragma unroll
        for (int ks = 0; ks < 4; ++ks) {
          B1h[base][ks] = B3h[base][ks];
          B1l[base][ks] = B3l[base][ks];
        }
    } else {
      // ---- final: X' = Bm·X, store fp32 row-major ----
#pragma unroll
      for (int tm = 0; tm < 2; ++tm)
#pragma unroll
        for (int tn = 0; tn < 2; ++tn) {
          f32x16 aH, aL;
#pragma unroll
          for (int r = 0; r < 16; ++r) { aH[r] = 0.f; aL[r] = 0.f; }
#pragma unroll
          for (int ks = 0; ks < 4; ++ks)
            mmtile3(B1h[tm][ks], B1l[tm][ks], B2h[tn][ks], B2l[tn][ks], aH, aL);
#pragma unroll
          for (int r = 0; r < 16; ++r) {
            float xv = aH[r] + aL[r] * INV_S;
            int row = 32 * tm + 4 * q + (r & 3) + ((r >> 2) << 3);
            int col = 32 * tn + ccol;
            G[row * 64 + col] = xv;
          }
        }
    }
  }
}

// ---------------------------------------------------------------------------
// B4: memory scan + read
// ---------------------------------------------------------------------------
__global__ __launch_bounds__(256) void mem_scan_kernel(const float* __restrict__ chunkS,
                                                       const float* __restrict__ qp,
                                                       const float* __restrict__ galpha,
                                                       float* __restrict__ Mst,
                                                       float* __restrict__ ybuf, int ci) {
  __shared__ float ql[CSz * Dsz];
  __shared__ float al[CSz];
  const int blk = blockIdx.x;
  const int bh = blk >> 4, eb = blk & 15;
  const int b = bh >> 4, h = bh & 15;
  const int tid = threadIdx.x;
  const int w = tid >> 6, lane = tid & 63;
  const int v = eb * 4 + w, k = lane;
  for (int i = tid; i < CSz * Dsz; i += 256) {
    int t = i >> 6, kk = i & 63;
    ql[i] = qp[(((size_t)b * Tsz + ci * CSz + t) * Hsz + h) * Dsz + kk];
  }
  if (tid < CSz) al[tid] = galpha[((size_t)b * Tsz + ci * CSz + tid) * Hsz + h];
  __syncthreads();
  float m = Mst[(size_t)bh * 4096 + v * 64 + k];
  const float* Xo = chunkS + (size_t)bh * CSz * 4096;
  for (int t = 0; t < CSz; ++t) {
    m = al[t] * m + Xo[(size_t)t * 4096 + v * 64 + k];
    float p = m * ql[t * 64 + k];
#pragma unroll
    for (int off = 32; off; off >>= 1) p += __shfl_xor(p, off, 64);
    if (lane == 0) ybuf[(((size_t)b * Tsz + ci * CSz + t) * Hsz + h) * Dsz + v] = p;
  }
  Mst[(size_t)bh * 4096 + v * 64 + k] = m;
}

// ---------------------------------------------------------------------------
extern "C" void kernel_launch(void* const* d_in, const int* in_sizes, int n_in,
                              void* d_out, int out_size, void* d_ws, size_t ws_size,
                              hipStream_t stream) {
  (void)in_sizes; (void)n_in; (void)out_size; (void)ws_size;
  const float* x   = (const float*)d_in[0];
  const float* Wq  = (const float*)d_in[1];
  const float* Wk  = (const float*)d_in[2];
  const float* Wv  = (const float*)d_in[3];
  const float* Wo  = (const float*)d_in[4];
  const float* cqw = (const float*)d_in[5];
  const float* cqb = (const float*)d_in[6];
  const float* ckw = (const float*)d_in[7];
  const float* ckb = (const float*)d_in[8];
  const float* cvw = (const float*)d_in[9];
  const float* cvb = (const float*)d_in[10];
  const float* Wa  = (const float*)d_in[11];
  const float* We  = (const float*)d_in[12];
  const float* Wt  = (const float*)d_in[13];
  const float* Wg  = (const float*)d_in[14];
  float* out = (float*)d_out;

  float* p = (float*)d_ws;
  const size_t NBTC = (size_t)Bsz * Tsz * Csz;
  const size_t NBTH = (size_t)Bsz * Tsz * Hsz;
  const size_t NMAT = (size_t)Bsz * Hsz * Dsz * Dsz;
  float* qlin = p; p += NBTC;
  float* klin = p; p += NBTC;
  float* vlin = p; p += NBTC;
  float* qp   = p; p += NBTC;
  float* kp   = p; p += NBTC;
  float* vp   = p; p += NBTC;
  float* ga   = p; p += NBTH;
  float* ge   = p; p += NBTH;
  float* gt   = p; p += NBTH;
  float* gg   = p; p += NBTH;
  float* Mst  = p; p += NMAT;
  float* Sst  = p; p += NMAT;
  float* chS  = p; p += (size_t)Bsz * Hsz * CSz * Dsz * Dsz;
  float* ybuf = p; p += NBTC;
  float* ynrm = p; p += NBTC;

  hipMemsetAsync(Mst, 0, NMAT * sizeof(float), stream);
  hipMemsetAsync(Sst, 0, NMAT * sizeof(float), stream);

  dim3 gg16(16, 16);
  gemm_nt<<<gg16, 256, 0, stream>>>(x, Wq, qlin, Bsz * Tsz, Csz, Csz);
  gemm_nt<<<gg16, 256, 0, stream>>>(x, Wk, klin, Bsz * Tsz, Csz, Csz);
  gemm_nt<<<gg16, 256, 0, stream>>>(x, Wv, vlin, Bsz * Tsz, Csz, Csz);
  gates_kernel<<<Bsz * Tsz, 64, 0, stream>>>(x, Wa, We, Wt, Wg, ga, ge, gt, gg);
  conv_kernel<<<Bsz * Tsz, 256, 0, stream>>>(qlin, cqw, cqb, qp, 1);
  conv_kernel<<<Bsz * Tsz, 256, 0, stream>>>(klin, ckw, ckb, kp, 1);
  conv_kernel<<<Bsz * Tsz, 256, 0, stream>>>(vlin, cvw, cvb, vp, 0);

  for (int ci = 0; ci < NCHUNK; ++ci) {
    mom_scan_kernel<<<Bsz * Hsz * 16, 256, 0, stream>>>(Mst, kp, vp, ge, gt, gg, Sst, chS, ci);
    pe_reg_kernel<<<Bsz * Hsz * CSz / 4, 256, 0, stream>>>(chS);
    mem_scan_kernel<<<Bsz * Hsz * 16, 256, 0, stream>>>(chS, qp, ga, Mst, ybuf, ci);
  }

  rms_kernel<<<Bsz * Tsz, 256, 0, stream>>>(ybuf, ynrm);
  gemm_nt<<<gg16, 256, 0, stream>>>(ynrm, Wo, out, Bsz * Tsz, Csz, Csz);
}